// Round 1
// baseline (221.487 us; speedup 1.0000x reference)
//
#include <hip/hip_runtime.h>

// out[b,h,i,j] = x[b,h,i,j] - max(p[h],eps) * log1p(max(a[h],eps) * max(i-j,0))
// Shapes hardcoded per reference: B=2, H=16, S=2048 (S=2^11, H=2^4 -> shift/mask decode).

#define EPS 0.01f
#define LN2 0.69314718055994530942f

__global__ __launch_bounds__(256) void ParallelKerpleLog_50216757625001_kernel(
    const float4* __restrict__ x,
    const float* __restrict__ bias_p,
    const float* __restrict__ bias_a,
    float4* __restrict__ out,
    int n4)
{
    __shared__ float sc[16];  // -max(p,eps) * ln2
    __shared__ float sa[16];  // max(a,eps)
    const int t = threadIdx.x;
    if (t < 16) {
        float p = fmaxf(bias_p[t], EPS);
        float a = fmaxf(bias_a[t], EPS);
        sc[t] = -p * LN2;
        sa[t] = a;
    }
    __syncthreads();

    const int stride = gridDim.x * blockDim.x;
    for (int idx = blockIdx.x * blockDim.x + t; idx < n4; idx += stride) {
        const int e = idx << 2;            // element index of .x lane (< 2^27, fits int)
        const int j = e & 2047;            // column
        const int i = (e >> 11) & 2047;    // row
        const int h = (e >> 22) & 15;      // head
        const float c = sc[h];             // wave-uniform -> LDS broadcast
        const float a = sa[h];

        const float4 v = x[idx];
        const int d0 = i - j;
        float r[4];
        const float vv[4] = {v.x, v.y, v.z, v.w};
        #pragma unroll
        for (int k = 0; k < 4; ++k) {
            int d = d0 - k;
            d = d > 0 ? d : 0;                         // tril clamp; log1p(0)=0 above diag
            const float tt = fmaf(a, (float)d, 1.0f);  // 1 + a*d
            const float l = __log2f(tt);               // v_log_f32
            r[k] = fmaf(c, l, vv[k]);                  // x + (-p*ln2)*log2(1+a*d)
        }
        out[idx] = make_float4(r[0], r[1], r[2], r[3]);
    }
}

extern "C" void kernel_launch(void* const* d_in, const int* in_sizes, int n_in,
                              void* d_out, int out_size, void* d_ws, size_t ws_size,
                              hipStream_t stream) {
    const float4* x      = (const float4*)d_in[0];
    const float*  bias_p = (const float*)d_in[1];
    const float*  bias_a = (const float*)d_in[2];
    float* out = (float*)d_out;

    const int n4 = out_size >> 2;  // 134217728 / 4 = 33554432 float4s
    const int threads = 256;
    const int blocks = 2048;       // grid-stride; ~8 blocks/CU across 256 CUs

    ParallelKerpleLog_50216757625001_kernel<<<blocks, threads, 0, stream>>>(
        x, bias_p, bias_a, (float4*)out, n4);
}

// Round 3
// 197.211 us; speedup vs baseline: 1.1231x; 1.1231x over previous
//
#include <hip/hip_runtime.h>

// out[b,h,i,j] = x[b,h,i,j] - max(p[h],eps) * log1p(max(a[h],eps) * max(i-j,0))
// B=2, H=16, S=2048. Block-uniform h: grid = 32 slabs (b*16+h) x 64 chunks.
// Each block: 256 threads x 64 float4 = 2^16 elements (32 matrix rows).

#define EPS 0.01f
#define LN2 0.69314718055994530942f

typedef float f32x4 __attribute__((ext_vector_type(4)));  // nontemporal builtins need ext_vector

__global__ __launch_bounds__(256) void ParallelKerpleLog_50216757625001_kernel(
    const f32x4* __restrict__ x,
    const float* __restrict__ bias_p,
    const float* __restrict__ bias_a,
    f32x4* __restrict__ out)
{
    const int bid = blockIdx.x;          // 2048 blocks
    const int h   = (bid >> 6) & 15;     // slab index low bits = head (slab = b*16+h)
    // h is block-uniform -> these are scalar (SGPR) ops, loaded once.
    const float a = fmaxf(bias_a[h], EPS);
    const float c = -fmaxf(bias_p[h], EPS) * LN2;   // bias = c * log2(1 + a*d)

    // base in float4 units: slab * 2^20 + chunk * 2^14
    const int base4 = ((bid >> 6) << 20) + ((bid & 63) << 14);
    const int idx0  = base4 + threadIdx.x;

    #pragma unroll
    for (int it = 0; it < 8; ++it) {
        int   id[8];
        f32x4 v[8];
        #pragma unroll
        for (int k = 0; k < 8; ++k) {
            id[k] = idx0 + (it * 8 + k) * 256;      // coalesced: wave covers 1KB/load
            v[k]  = __builtin_nontemporal_load(&x[id[k]]);
        }
        f32x4 r[8];
        #pragma unroll
        for (int k = 0; k < 8; ++k) {
            const int e  = id[k] << 2;              // element index (< 2^27)
            const int j  = e & 2047;                // column
            const int i  = (e >> 11) & 2047;        // row
            const int d0 = i - j;
            #pragma unroll
            for (int q = 0; q < 4; ++q) {
                int d = d0 - q;
                d = d > 0 ? d : 0;                               // tril clamp; log1p(0)=0
                r[k][q] = fmaf(c, __log2f(fmaf(a, (float)d, 1.0f)), v[k][q]);
            }
        }
        #pragma unroll
        for (int k = 0; k < 8; ++k) {
            __builtin_nontemporal_store(r[k], &out[id[k]]);
        }
    }
}

extern "C" void kernel_launch(void* const* d_in, const int* in_sizes, int n_in,
                              void* d_out, int out_size, void* d_ws, size_t ws_size,
                              hipStream_t stream) {
    const f32x4* x       = (const f32x4*)d_in[0];
    const float*  bias_p = (const float*)d_in[1];
    const float*  bias_a = (const float*)d_in[2];
    f32x4* out = (f32x4*)d_out;

    // 32 slabs x 64 chunks = 2048 blocks; 2048*256*64 float4 = 2^25 = exact cover.
    ParallelKerpleLog_50216757625001_kernel<<<2048, 256, 0, stream>>>(
        x, bias_p, bias_a, out);
}

// Round 4
// 196.810 us; speedup vs baseline: 1.1254x; 1.0020x over previous
//
#include <hip/hip_runtime.h>

// out[b,h,i,j] = x[b,h,i,j] - max(p[h],eps) * log1p(max(a[h],eps) * max(i-j,0))
// B=2, H=16, S=2048. Block-uniform h: grid = 32 slabs (b*16+h) x 64 chunks.
// Each block: 256 threads x 64 float4. 2-deep software pipeline (batch=8) so
// loads for batch n+1 are in flight while batch n computes/stores.

#define EPS 0.01f
#define LN2 0.69314718055994530942f

typedef float f32x4 __attribute__((ext_vector_type(4)));  // nontemporal builtins need ext_vector

__device__ __forceinline__ void load8(const f32x4* __restrict__ x, int idx0, int it,
                                      f32x4 (&buf)[8]) {
    #pragma unroll
    for (int k = 0; k < 8; ++k)
        buf[k] = __builtin_nontemporal_load(&x[idx0 + (it * 8 + k) * 256]);
}

__device__ __forceinline__ void proc8(f32x4* __restrict__ out, int idx0, int it,
                                      const f32x4 (&buf)[8], float a, float c) {
    #pragma unroll
    for (int k = 0; k < 8; ++k) {
        const int id = idx0 + (it * 8 + k) * 256;
        const int e  = id << 2;              // element index (< 2^27)
        const int j  = e & 2047;             // column
        const int i  = (e >> 11) & 2047;     // row
        const int d0 = i - j;
        f32x4 r;
        #pragma unroll
        for (int q = 0; q < 4; ++q) {
            int d = d0 - q;
            d = d > 0 ? d : 0;               // tril clamp; log1p(0)=0 above diag
            r[q] = fmaf(c, __log2f(fmaf(a, (float)d, 1.0f)), buf[k][q]);
        }
        __builtin_nontemporal_store(r, &out[id]);
    }
}

__global__ __launch_bounds__(256) void ParallelKerpleLog_50216757625001_kernel(
    const f32x4* __restrict__ x,
    const float* __restrict__ bias_p,
    const float* __restrict__ bias_a,
    f32x4* __restrict__ out)
{
    const int bid = blockIdx.x;          // 2048 blocks
    const int h   = (bid >> 6) & 15;     // slab = b*16+h -> block-uniform head
    const float a = fmaxf(bias_a[h], EPS);
    const float c = -fmaxf(bias_p[h], EPS) * LN2;   // bias = c * log2(1 + a*d)

    const int base4 = ((bid >> 6) << 20) + ((bid & 63) << 14);
    const int idx0  = base4 + threadIdx.x;

    f32x4 vA[8], vB[8];                  // static double buffer (register-resident)

    load8(x, idx0, 0, vA);
    #pragma unroll 1
    for (int g = 0; g < 4; ++g) {        // 2 batches per iteration, static A/B roles
        const int itA = 2 * g, itB = 2 * g + 1;
        load8(x, idx0, itB, vB);         // prefetch B while A computes
        proc8(out, idx0, itA, vA, a, c);
        if (g < 3) load8(x, idx0, itA + 2, vA);  // prefetch next A while B computes
        proc8(out, idx0, itB, vB, a, c);
    }
}

extern "C" void kernel_launch(void* const* d_in, const int* in_sizes, int n_in,
                              void* d_out, int out_size, void* d_ws, size_t ws_size,
                              hipStream_t stream) {
    const f32x4* x       = (const f32x4*)d_in[0];
    const float*  bias_p = (const float*)d_in[1];
    const float*  bias_a = (const float*)d_in[2];
    f32x4* out = (f32x4*)d_out;

    // 32 slabs x 64 chunks = 2048 blocks; 2048*256*64 float4 = 2^25 = exact cover.
    ParallelKerpleLog_50216757625001_kernel<<<2048, 256, 0, stream>>>(
        x, bias_p, bias_a, out);
}